// Round 7
// baseline (255.611 us; speedup 1.0000x reference)
//
#include <hip/hip_runtime.h>
#include <hip/hip_bf16.h>
#include <hip/hip_fp16.h>

// CRF NLL, B=256, T=1024, L=64. Linear-domain recursion, fp16-pair packed dot2
// formulation. ONE WAVE runs BOTH the fwd chain (alpha, t=1..h) and bwd chain
// (beta, t=sl..h+1) of the same batch, manually interleaved instruction-by-
// instruction so the two independent dependency chains fill each other's
// hazard/latency stalls (single wave per SIMD otherwise exposes every stall).
// Step counts differ by <=1 by construction. alpha_h,beta_h meet in-wave:
// z = sum_j alpha_j beta_j, score = ln2*(log2 z + Kf + Kb). Gold path = 2nd role.

typedef _Float16 h2 __attribute__((ext_vector_type(2)));
#define B2U(x) __builtin_bit_cast(unsigned, x)
#define U2H(x) __builtin_bit_cast(h2, x)
#define L2E 1.44269504088896340736f
#define LN2 0.69314718055994530942f
#define EXPE(p) __builtin_amdgcn_exp2f((p) * L2E)
#define SBAR __builtin_amdgcn_sched_barrier(0)

#define W_ALL(M) M(0) M(1) M(2) M(3) M(4) M(5) M(6) M(7) M(8) M(9) M(10) M(11) \
 M(12) M(13) M(14) M(15) M(16) M(17) M(18) M(19) M(20) M(21) M(22) M(23) M(24) \
 M(25) M(26) M(27) M(28) M(29) M(30) M(31)

#define DECLWF(q) unsigned WF##q;
#define DECLWB(q) unsigned WB##q;
#define LOADWF(q) WF##q = B2U(__builtin_amdgcn_cvt_pkrtz(EXPE(tcol[(2*(q))*66]), EXPE(tcol[(2*(q)+1)*66])));
#define LOADWB(q) WB##q = B2U(__builtin_amdgcn_cvt_pkrtz(EXPE(trow[2*(q)]), EXPE(trow[2*(q)+1])));
#define PINWF(q)  asm volatile("" : "+v"(WF##q));
#define PINWB(q)  asm volatile("" : "+v"(WB##q));

// readlane broadcasts (even lanes of packed pair vector)
#define RLD(q,c) int u##q##c = __builtin_amdgcn_readlane((int)P##c, 2*(q));
#define RL16A(c) RLD(0,c) RLD(1,c) RLD(2,c) RLD(3,c) RLD(4,c) RLD(5,c) RLD(6,c) RLD(7,c) \
                 RLD(8,c) RLD(9,c) RLD(10,c) RLD(11,c) RLD(12,c) RLD(13,c) RLD(14,c) RLD(15,c)
#define RL16B(c) RLD(16,c) RLD(17,c) RLD(18,c) RLD(19,c) RLD(20,c) RLD(21,c) RLD(22,c) RLD(23,c) \
                 RLD(24,c) RLD(25,c) RLD(26,c) RLD(27,c) RLD(28,c) RLD(29,c) RLD(30,c) RLD(31,c)

#if __has_builtin(__builtin_amdgcn_fdot2)
#define DOTQ(q,c,W,acc) acc##c = __builtin_amdgcn_fdot2(U2H((unsigned)u##q##c), U2H(W##q), acc##c, false);
#else
#define DOTQ(q,c,W,acc) { h2 _u = U2H((unsigned)u##q##c), _w = U2H(W##q); \
    acc##c = fmaf((float)_u[0], (float)_w[0], fmaf((float)_u[1], (float)_w[1], acc##c)); }
#endif
#define DOT16A(c,W) \
    DOTQ(0,c,W,s0)  DOTQ(1,c,W,s1)  DOTQ(2,c,W,s2)  DOTQ(3,c,W,s3) \
    DOTQ(4,c,W,s0)  DOTQ(5,c,W,s1)  DOTQ(6,c,W,s2)  DOTQ(7,c,W,s3) \
    DOTQ(8,c,W,s0)  DOTQ(9,c,W,s1)  DOTQ(10,c,W,s2) DOTQ(11,c,W,s3) \
    DOTQ(12,c,W,s0) DOTQ(13,c,W,s1) DOTQ(14,c,W,s2) DOTQ(15,c,W,s3)
#define DOT16B(c,W) \
    DOTQ(16,c,W,s0) DOTQ(17,c,W,s1) DOTQ(18,c,W,s2) DOTQ(19,c,W,s3) \
    DOTQ(20,c,W,s0) DOTQ(21,c,W,s1) DOTQ(22,c,W,s2) DOTQ(23,c,W,s3) \
    DOTQ(24,c,W,s0) DOTQ(25,c,W,s1) DOTQ(26,c,W,s2) DOTQ(27,c,W,s3) \
    DOTQ(28,c,W,s0) DOTQ(29,c,W,s1) DOTQ(30,c,W,s2) DOTQ(31,c,W,s3)

#define ROWC(i) pb[(((i) < 0) ? 0 : (((i) > 1023) ? 1023 : (i))) * 64]

// quad_perm [1,0,3,2] pair swap; VALU DPP.
#define DPPSWAP(x) __uint_as_float((unsigned)__builtin_amdgcn_mov_dpp( \
    (int)__float_as_uint(x), 0xB1, 0xF, 0xF, true))

// Interleaved super-step: one fwd step (emission EF applied after matvec) and
// one bwd step (emission EB applied before matvec). Exact pow-2 renorm, k from
// lane0 exponent + 5 bias.
#define STEP2(EF, EB) { \
    unsigned abF = (unsigned)__builtin_amdgcn_readfirstlane((int)__float_as_uint(aF)); \
    unsigned abB = (unsigned)__builtin_amdgcn_readfirstlane((int)__float_as_uint(aB)); \
    int kF = (int)((abF >> 23) & 255u) - 122; \
    int kB = (int)((abB >> 23) & 255u) - 122; \
    KF += kF; KB += kB; \
    float scF = __uint_as_float((unsigned)(127 - kF) << 23); \
    float scB = __uint_as_float((unsigned)(127 - kB) << 23); \
    float xF = aF * scF; \
    float xB = (aB * scB) * (EB); \
    float xoF = DPPSWAP(xF); \
    float xoB = DPPSWAP(xB); \
    unsigned PF = B2U(__builtin_amdgcn_cvt_pkrtz(xF, xoF)); \
    unsigned PB = B2U(__builtin_amdgcn_cvt_pkrtz(xB, xoB)); \
    float s0F=0.f,s1F=0.f,s2F=0.f,s3F=0.f; \
    float s0B=0.f,s1B=0.f,s2B=0.f,s3B=0.f; \
    RL16A(F) RL16A(B) \
    SBAR; \
    DOT16A(F,WF) DOT16A(B,WB) \
    RL16B(F) RL16B(B) \
    SBAR; \
    DOT16B(F,WF) DOT16B(B,WB) \
    float sF = (s0F + s1F) + (s2F + s3F); \
    float sB = (s0B + s1B) + (s2B + s3B); \
    aF = sF * (EF); \
    aB = sB; }

// Single bwd step (for the +1 length tail).
#define STEPB1(EB) { \
    unsigned abB = (unsigned)__builtin_amdgcn_readfirstlane((int)__float_as_uint(aB)); \
    int kB = (int)((abB >> 23) & 255u) - 122; \
    KB += kB; \
    float scB = __uint_as_float((unsigned)(127 - kB) << 23); \
    float xB = (aB * scB) * (EB); \
    float xoB = DPPSWAP(xB); \
    unsigned PB = B2U(__builtin_amdgcn_cvt_pkrtz(xB, xoB)); \
    float s0B=0.f,s1B=0.f,s2B=0.f,s3B=0.f; \
    RL16A(B) \
    SBAR; \
    DOT16A(B,WB) \
    RL16B(B) \
    SBAR; \
    DOT16B(B,WB) \
    aB = (s0B + s1B) + (s2B + s3B); }

__global__ __launch_bounds__(64) __attribute__((amdgpu_waves_per_eu(1, 1)))
void crf_kernel(const float* __restrict__ pred,
                const float* __restrict__ trans,
                const int*   __restrict__ ref,
                const int*   __restrict__ seqlen,
                float* __restrict__ out)
{
    const int role = blockIdx.x >> 8;
    const int b    = blockIdx.x & 255;
    const int lane = threadIdx.x;
    const int sl   = seqlen[b];
    const int h    = (sl + 1) >> 1;

    if (role == 1) {
        // ---- gold-path score ----
        const int*   rb = ref  + b * 1024;
        const float* pg = pred + (size_t)b * 65536;
        float acc = 0.f;
        for (int t = lane; t <= sl; t += 64) {
            int from = (t == 0) ? 64 : rb[t - 1];
            int cur  = (t < sl) ? rb[t] : 65;
            acc += trans[from * 66 + cur];
            if (t < sl) acc += pg[t * 64 + cur];
        }
        #pragma unroll
        for (int off = 32; off; off >>= 1) acc += __shfl_xor(acc, off, 64);
        if (lane == 0) atomicAdd(out, -acc);
        return;
    }

    // ---- paired fwd+bwd chains of batch b in one wave ----
    const float* pb   = pred + (size_t)b * 65536 + lane;
    const float* tcol = trans + lane;        // fwd table: V[i][lane]
    const float* trow = trans + lane * 66;   // bwd table: V[lane][i]

    W_ALL(DECLWF) W_ALL(DECLWB)
    W_ALL(LOADWF) W_ALL(LOADWB)
    W_ALL(PINWF)  W_ALL(PINWB)

    float aF = __builtin_amdgcn_exp2f((pb[0] + trans[64 * 66 + lane]) * L2E);
    float aB = __builtin_amdgcn_exp2f(trow[65] * L2E);
    int KF = 0, KB = 0;

    const int nF = h - 1;        // fwd steps  (rows 1 .. h-1)
    const int nB = sl - h;       // bwd steps  (rows sl-1 .. h), nB - nF in {0,1}
    int rF = 1, rB = sl - 1;
    int n4 = nF;                 // shared loop count = min(nF, nB) = nF

    float EF0 = EXPE(ROWC(rF)),     EF1 = EXPE(ROWC(rF + 1)),
          EF2 = EXPE(ROWC(rF + 2)), EF3 = EXPE(ROWC(rF + 3));
    float EB0 = EXPE(ROWC(rB)),     EB1 = EXPE(ROWC(rB - 1)),
          EB2 = EXPE(ROWC(rB - 2)), EB3 = EXPE(ROWC(rB - 3));

    while (n4 >= 4) {
        float FF0 = ROWC(rF + 4), FF1 = ROWC(rF + 5), FF2 = ROWC(rF + 6), FF3 = ROWC(rF + 7);
        float FB0 = ROWC(rB - 4), FB1 = ROWC(rB - 5), FB2 = ROWC(rB - 6), FB3 = ROWC(rB - 7);
        STEP2(EF0, EB0) STEP2(EF1, EB1) STEP2(EF2, EB2) STEP2(EF3, EB3)
        EF0 = EXPE(FF0); EF1 = EXPE(FF1); EF2 = EXPE(FF2); EF3 = EXPE(FF3);
        EB0 = EXPE(FB0); EB1 = EXPE(FB1); EB2 = EXPE(FB2); EB3 = EXPE(FB3);
        rF += 4; rB -= 4; n4 -= 4;
    }
    if (n4 > 0) { STEP2(EF0, EB0) }
    if (n4 > 1) { STEP2(EF1, EB1) }
    if (n4 > 2) { STEP2(EF2, EB2) }
    if (nB > nF) {
        float EBn = (n4 == 0) ? EB0 : (n4 == 1) ? EB1 : (n4 == 2) ? EB2 : EB3;
        STEPB1(EBn)
    }

    // combine in-wave: Z = sum_j alpha_h[j] * beta_h[j]
    float z = aF * aB;
    #pragma unroll
    for (int off = 32; off; off >>= 1) z += __shfl_xor(z, off, 64);
    if (lane == 0) {
        float res = LN2 * (__builtin_amdgcn_logf(z) + (float)(KF + KB));
        atomicAdd(out, res);
    }
}

extern "C" void kernel_launch(void* const* d_in, const int* in_sizes, int n_in,
                              void* d_out, int out_size, void* d_ws, size_t ws_size,
                              hipStream_t stream) {
    const float* pred   = (const float*)d_in[0];
    const float* trans  = (const float*)d_in[1];
    const int*   ref    = (const int*)d_in[2];
    const int*   seqlen = (const int*)d_in[3];
    float* out = (float*)d_out;
    hipMemsetAsync(out, 0, sizeof(float), stream);
    crf_kernel<<<512, 64, 0, stream>>>(pred, trans, ref, seqlen, out);
}

// Round 8
// 183.740 us; speedup vs baseline: 1.3912x; 1.3912x over previous
//
#include <hip/hip_runtime.h>
#include <hip/hip_bf16.h>
#include <hip/hip_fp16.h>

// CRF NLL, B=256, T=1024, L=64. Linear-domain recursion, fp16-pair dot2 matvec.
// Broadcast of the renormalized state vector is done via LDS same-address
// ds_read_b128 (hardware broadcast, ~4cy) instead of v_readlane (~8cy each, the
// R1-R7 throughput wall). Per step: 1 ds_write_b32 (64 distinct slots, odd lanes
// park in slots 32..63 -> no exec divergence) + 8 broadcast b128 reads + 32
// v_dot2_f32_f16. V=exp(trans) in 32 pinned packed-half2 VGPRs. Exact pow-2
// renorm per step (k from lane-0 exponent, -5 bias keeps fp16 pack in range).
// Meet-in-the-middle: fwd wave (t=1..h) / bwd wave (t=sl..h+1) as separate
// 1-wave blocks (serial chains overlap on different SIMDs), gold wave, tiny
// combine kernel via workspace.

typedef _Float16 h2 __attribute__((ext_vector_type(2)));
#define B2U(x) __builtin_bit_cast(unsigned, x)
#define U2H(x) __builtin_bit_cast(h2, x)
#define L2E 1.44269504088896340736f
#define LN2 0.69314718055994530942f
#define EXPE(p) __builtin_amdgcn_exp2f((p) * L2E)

#define W_ALL(M) M(0) M(1) M(2) M(3) M(4) M(5) M(6) M(7) M(8) M(9) M(10) M(11) \
 M(12) M(13) M(14) M(15) M(16) M(17) M(18) M(19) M(20) M(21) M(22) M(23) M(24) \
 M(25) M(26) M(27) M(28) M(29) M(30) M(31)

#define DECLW(q) unsigned W##q;
#define LOADF(q) W##q = B2U(__builtin_amdgcn_cvt_pkrtz(EXPE(tcol[(2*(q))*66]), EXPE(tcol[(2*(q)+1)*66])));
#define LOADB(q) W##q = B2U(__builtin_amdgcn_cvt_pkrtz(EXPE(trow[2*(q)]), EXPE(trow[2*(q)+1])));
#define PINW(q)  asm volatile("" : "+v"(W##q));

#if __has_builtin(__builtin_amdgcn_fdot2)
#define DOT(u, q, acc) acc = __builtin_amdgcn_fdot2(U2H(u), U2H(W##q), acc, false);
#else
#define DOT(u, q, acc) { h2 _u = U2H(u), _w = U2H(W##q); \
    acc = fmaf((float)_u[0], (float)_w[0], fmaf((float)_u[1], (float)_w[1], acc)); }
#endif

#define ROWF(i) pb[(((i) < 0) ? 0 : (((i) > 1023) ? 1023 : (i))) * 64]

// quad_perm [1,0,3,2] pair swap; full-rate VALU DPP.
#define DPPSWAP(x) __uint_as_float((unsigned)__builtin_amdgcn_mov_dpp( \
    (int)__float_as_uint(x), 0xB1, 0xF, 0xF, true))

// One step. fwd: a' = E .* (V^T x); bwd: a' = V (E .* x); x = a * 2^-k.
// Broadcast x via LDS: write packed pair, read back with 8 same-address b128.
#define STEPX(E) { \
    unsigned abits = (unsigned)__builtin_amdgcn_readfirstlane((int)__float_as_uint(a)); \
    int k = (int)((abits >> 23) & 255u) - 122; \
    K += k; \
    float sc = __uint_as_float((unsigned)(127 - k) << 23); \
    float x = FWD ? a * sc : (a * sc) * (E); \
    float xo = DPPSWAP(x); \
    sh[saddr] = B2U(__builtin_amdgcn_cvt_pkrtz(x, xo)); \
    uint4 q0 = shv[0], q1 = shv[1], q2 = shv[2], q3 = shv[3], \
          q4 = shv[4], q5 = shv[5], q6 = shv[6], q7 = shv[7]; \
    float s0 = 0.f, s1 = 0.f, s2 = 0.f, s3 = 0.f; \
    DOT(q0.x,0,s0)  DOT(q0.y,1,s1)  DOT(q0.z,2,s2)  DOT(q0.w,3,s3) \
    DOT(q1.x,4,s0)  DOT(q1.y,5,s1)  DOT(q1.z,6,s2)  DOT(q1.w,7,s3) \
    DOT(q2.x,8,s0)  DOT(q2.y,9,s1)  DOT(q2.z,10,s2) DOT(q2.w,11,s3) \
    DOT(q3.x,12,s0) DOT(q3.y,13,s1) DOT(q3.z,14,s2) DOT(q3.w,15,s3) \
    DOT(q4.x,16,s0) DOT(q4.y,17,s1) DOT(q4.z,18,s2) DOT(q4.w,19,s3) \
    DOT(q5.x,20,s0) DOT(q5.y,21,s1) DOT(q5.z,22,s2) DOT(q5.w,23,s3) \
    DOT(q6.x,24,s0) DOT(q6.y,25,s1) DOT(q6.z,26,s2) DOT(q6.w,27,s3) \
    DOT(q7.x,28,s0) DOT(q7.y,29,s1) DOT(q7.z,30,s2) DOT(q7.w,31,s3) \
    float s = (s0 + s1) + (s2 + s3); \
    a = FWD ? s * (E) : s; }

template<bool FWD>
__device__ __forceinline__ void chain(const float* __restrict__ pred,
                                      const float* __restrict__ trans,
                                      unsigned* sh,
                                      int b, int lane, int sl, int h,
                                      float* __restrict__ wsV,
                                      int* __restrict__ wsK)
{
    const float* pb   = pred + (size_t)b * 65536 + lane;
    const float* tcol = trans + lane;        // fwd: V[i][lane]
    const float* trow = trans + lane * 66;   // bwd: V[lane][i]
    (void)tcol; (void)trow;
    const uint4* shv  = (const uint4*)sh;
    // even lane e -> slot e/2 (the pair the dots read); odd lanes park in 32..63
    const int saddr = (lane >> 1) + ((lane & 1) << 5);

    W_ALL(DECLW)
    if (FWD) { W_ALL(LOADF) } else { W_ALL(LOADB) }
    W_ALL(PINW)

    float a;
    int   K = 0;
    if (FWD) a = EXPE(pb[0] + trans[64 * 66 + lane]);
    else     a = EXPE(trow[65]);

    const int dir = FWD ? 1 : -1;
    int n = FWD ? h - 1 : sl - h;
    int r = FWD ? 1 : sl - 1;

    float E0 = EXPE(ROWF(r)), E1 = EXPE(ROWF(r + dir)),
          E2 = EXPE(ROWF(r + 2 * dir)), E3 = EXPE(ROWF(r + 3 * dir));
    while (n >= 4) {
        float F0 = ROWF(r + 4 * dir), F1 = ROWF(r + 5 * dir),
              F2 = ROWF(r + 6 * dir), F3 = ROWF(r + 7 * dir);
        STEPX(E0) STEPX(E1) STEPX(E2) STEPX(E3)
        E0 = EXPE(F0); E1 = EXPE(F1); E2 = EXPE(F2); E3 = EXPE(F3);
        r += 4 * dir; n -= 4;
    }
    if (n > 0) { STEPX(E0) --n; }
    if (n > 0) { STEPX(E1) --n; }
    if (n > 0) { STEPX(E2) }

    wsV[b * 64 + lane] = a;
    if (lane == 0) wsK[b] = K;
}

__global__ __launch_bounds__(64) __attribute__((amdgpu_waves_per_eu(1, 1)))
void chain_kernel(const float* __restrict__ pred,
                  const float* __restrict__ trans,
                  const int*   __restrict__ ref,
                  const int*   __restrict__ seqlen,
                  float* __restrict__ wsA, float* __restrict__ wsB,
                  int* __restrict__ wsKf, int* __restrict__ wsKb,
                  float* __restrict__ out)
{
    __shared__ unsigned sh[64];
    const int role = blockIdx.x >> 8;
    const int b    = blockIdx.x & 255;
    const int lane = threadIdx.x;
    const int sl   = seqlen[b];
    const int h    = (sl + 1) >> 1;

    if (role == 0) {
        chain<true>(pred, trans, sh, b, lane, sl, h, wsA, wsKf);
    } else if (role == 1) {
        chain<false>(pred, trans, sh, b, lane, sl, h, wsB, wsKb);
    } else {
        // gold-path score
        const int*   rb = ref  + b * 1024;
        const float* pg = pred + (size_t)b * 65536;
        float acc = 0.f;
        for (int t = lane; t <= sl; t += 64) {
            int from = (t == 0) ? 64 : rb[t - 1];
            int cur  = (t < sl) ? rb[t] : 65;
            acc += trans[from * 66 + cur];
            if (t < sl) acc += pg[t * 64 + cur];
        }
        #pragma unroll
        for (int off = 32; off; off >>= 1) acc += __shfl_xor(acc, off, 64);
        if (lane == 0) atomicAdd(out, -acc);
    }
}

__global__ __launch_bounds__(64) void combine_kernel(
    const float* __restrict__ wsA, const float* __restrict__ wsB,
    const int* __restrict__ wsKf, const int* __restrict__ wsKb,
    float* __restrict__ out)
{
    const int b = blockIdx.x, lane = threadIdx.x;
    float z = wsA[b * 64 + lane] * wsB[b * 64 + lane];
    #pragma unroll
    for (int off = 32; off; off >>= 1) z += __shfl_xor(z, off, 64);
    if (lane == 0) {
        float res = LN2 * (__builtin_amdgcn_logf(z) + (float)(wsKf[b] + wsKb[b]));
        atomicAdd(out, res);
    }
}

extern "C" void kernel_launch(void* const* d_in, const int* in_sizes, int n_in,
                              void* d_out, int out_size, void* d_ws, size_t ws_size,
                              hipStream_t stream) {
    const float* pred   = (const float*)d_in[0];
    const float* trans  = (const float*)d_in[1];
    const int*   ref    = (const int*)d_in[2];
    const int*   seqlen = (const int*)d_in[3];
    float* out = (float*)d_out;

    float* wsA  = (float*)d_ws;            // 256*64 f32
    float* wsB  = wsA + 256 * 64;          // 256*64 f32
    int*   wsKf = (int*)(wsB + 256 * 64);  // 256 i32
    int*   wsKb = wsKf + 256;              // 256 i32

    hipMemsetAsync(out, 0, sizeof(float), stream);
    chain_kernel<<<768, 64, 0, stream>>>(pred, trans, ref, seqlen,
                                         wsA, wsB, wsKf, wsKb, out);
    combine_kernel<<<256, 64, 0, stream>>>(wsA, wsB, wsKf, wsKb, out);
}